// Round 13
// baseline (237.088 us; speedup 1.0000x reference)
//
#include <hip/hip_runtime.h>

// GCNEncoder: h1 = x@W1; hag = relu(A_norm h1 + b1); h2 = hag@W2; out = A_norm h2 + b2
// A_norm (self loops): out[v] = dinv[v]^2 h[v] + sum_{e:dst=v} dinv[src]dinv[v] h[src]
// Established: float inputs f32 (probed), edges int64 (probed), output f32.
// h1/h2 bf16. GEMM1 = MFMA 16x16x32. Counting-sort CSR + hierarchical scan (R12).
// R13: (a) GEMM2 fused into agg1 — after the shfl_xor butterfly every lane holds
// the full 128-wide hag row; bias+relu then h2[lane] = sum_k hag[k]*W2[k][lane]
// via readlane-broadcast + 128 FMA (wt2 16KB L1-resident). Kills gemm2 dispatch
// + hag 15MB round-trip; hag stays f32 into the matvec. (b) scanB merged into
// scanC (redundant 235-elem LDS scan per block). 13 -> 10 dispatches.

#define GCN_IN 256
#define GCN_HID 128
#define GCN_OUT 64

#define BKT 128          // nodes per bucket (dst >> 7)
#define SBE 4096         // edges per superblock
#define SRCM 0x1FFFFFFu  // 25-bit src mask

typedef unsigned short ushort_t;
typedef __attribute__((ext_vector_type(8))) short short8;     // 8 bf16 (4 VGPR)
typedef __attribute__((ext_vector_type(8))) unsigned short ushort8;
typedef __attribute__((ext_vector_type(4))) float f32x4;

__device__ inline float bf2f(ushort_t u) {
  union { unsigned int i; float f; } x; x.i = ((unsigned int)u) << 16; return x.f;
}
__device__ inline ushort_t f2bf(float f) {
  union { float f; unsigned int i; } u; u.f = f;
  unsigned int r = u.i + 0x7FFFu + ((u.i >> 16) & 1u);  // RNE
  return (ushort_t)(r >> 16);
}

// ---------------- dtype probe ----------------
// flags[0]: 1 = float inputs f32, 0 = bf16.  flags[1]: 1 = edges int64, 0 = int32.
__global__ void probe_kernel(const ushort_t* __restrict__ xu,
                             const int* __restrict__ ei,
                             int* __restrict__ flags) {
  int lane = threadIdx.x;  // 64 threads
  int c = 0, nz = 0;
  for (int i = lane; i < 128; i += 64) {
    ushort_t u = xu[2 * i];
    int e = (u >> 7) & 0xFF;
    c += (e >= 100 && e <= 140) ? 1 : 0;
    nz += (ei[2 * i + 1] != 0) ? 1 : 0;
  }
  for (int off = 32; off > 0; off >>= 1) {
    c += __shfl_down(c, off);
    nz += __shfl_down(nz, off);
  }
  if (lane == 0) {
    flags[0] = (c >= 64) ? 0 : 1;
    flags[1] = (nz == 0) ? 1 : 0;
  }
}

// ---- Pass A: per-superblock LDS bucket histogram -> Hmat[bin*nsb+sb] ----
__global__ void hist_kernel(const int* __restrict__ ei, int E,
                            int* __restrict__ Hmat, int nsb, int nbin,
                            const int* __restrict__ flags) {
  __shared__ int hist[256];
  int t = threadIdx.x;
  int sb = blockIdx.x;
  hist[t] = 0;
  __syncthreads();
  int base = sb * SBE;
  int end = base + SBE; if (end > E) end = E;
  bool i64 = flags[1] != 0;
  for (int i = base + t; i < end; i += 256) {
    int d = i64 ? ei[2 * E + 2 * i] : ei[E + i];
    atomicAdd(&hist[d >> 7], 1);            // LDS atomic
  }
  __syncthreads();
  for (int b = t; b < nbin; b += 256)
    Hmat[b * nsb + sb] = hist[b];
}

// ---- hierarchical exclusive scan of Hmat (bin-major) ----
// scanA: block b reduces its row Hmat[b*nsb .. +nsb) -> binsum[b] (raw sums)
__global__ void scanA_kernel(const int* __restrict__ Hmat, int nsb,
                             int* __restrict__ binsum) {
  __shared__ int red[256];
  int t = threadIdx.x;
  const int* row = Hmat + (size_t)blockIdx.x * nsb;
  int s = 0;
  for (int i = t; i < nsb; i += 256) s += row[i];
  red[t] = s;
  __syncthreads();
  for (int off = 128; off > 0; off >>= 1) {
    if (t < off) red[t] += red[t + off];
    __syncthreads();
  }
  if (t == 0) binsum[blockIdx.x] = red[0];
}

// scanC: block b (redundantly) scans raw binsum in LDS for its seed, then scans
// its own row in place. (R12's scanB launch merged in.)
__global__ void scanC_kernel(int* __restrict__ Hmat, int nsb,
                             const int* __restrict__ binsum, int nbin) {
  __shared__ int bred[256];
  __shared__ int red[256];
  int t = threadIdx.x;
  int bs = (t < nbin) ? binsum[t] : 0;
  bred[t] = bs;
  __syncthreads();
  for (int off = 1; off < 256; off <<= 1) {
    int u = (t >= off) ? bred[t - off] : 0;
    __syncthreads();
    bred[t] += u;
    __syncthreads();
  }
  __shared__ int seed_sh;
  if (t == (int)blockIdx.x) seed_sh = bred[t] - bs;   // exclusive prefix of bins
  __syncthreads();
  int seed = seed_sh;
  int* row = Hmat + (size_t)blockIdx.x * nsb;
  int self = (t < nsb) ? row[t] : 0;
  red[t] = self;
  __syncthreads();
  for (int off = 1; off < 256; off <<= 1) {
    int u = (t >= off) ? red[t - off] : 0;
    __syncthreads();
    red[t] += u;
    __syncthreads();
  }
  if (t < nsb) row[t] = seed + red[t] - self;  // exclusive + seed
}

// ---- Pass C: stage edges bucket-sorted; LDS cursors seeded from scanned Hmat.
// Packed u32: src (25b) | dst_local (7b) << 25.
__global__ void stage2_kernel(const int* __restrict__ ei, int E,
                              const int* __restrict__ Hscan, int nsb, int nbin,
                              unsigned int* __restrict__ stage,
                              const int* __restrict__ flags) {
  __shared__ int cur[256];
  int t = threadIdx.x;
  int sb = blockIdx.x;
  for (int b = t; b < nbin; b += 256)
    cur[b] = Hscan[b * nsb + sb];
  __syncthreads();
  int base = sb * SBE;
  int end = base + SBE; if (end > E) end = E;
  bool i64 = flags[1] != 0;
  for (int i = base + t; i < end; i += 256) {
    int s, d;
    if (i64) { s = ei[2 * i]; d = ei[2 * E + 2 * i]; }
    else     { s = ei[i];     d = ei[E + i]; }
    int pos = atomicAdd(&cur[d >> 7], 1);   // LDS atomic
    stage[pos] = (unsigned int)s | ((unsigned int)(d & 127) << 25);
  }
}

// ---- Pass D: block per bucket. Local hist -> local scan -> row_ptr + dinv +
// LDS cursors -> scatter csr_src within the bucket's contiguous window.
__global__ void scatter_kernel(const unsigned int* __restrict__ stage,
                               const int* __restrict__ Hmat, int nsb, int nbin,
                               int* __restrict__ csr_src,
                               int* __restrict__ row_ptr,
                               float* __restrict__ dinv, int n, int E) {
  __shared__ int lcnt[BKT];
  __shared__ int lscan[BKT];
  __shared__ int lcur[BKT];
  const int t = threadIdx.x;                // 256 threads
  const int b = blockIdx.x;
  const int node0 = b * BKT;
  const int nn = (n - node0 < BKT) ? (n - node0) : BKT;
  const int rb = Hmat[b * nsb];
  const int re = (b + 1 < nbin) ? Hmat[(b + 1) * nsb] : E;
  if (t < BKT) lcnt[t] = 0;
  __syncthreads();
  for (int i = rb + t; i < re; i += 256)
    atomicAdd(&lcnt[stage[i] >> 25], 1);    // LDS atomic, 128 counters
  __syncthreads();
  if (t < BKT) lscan[t] = lcnt[t];
  __syncthreads();
  for (int off = 1; off < BKT; off <<= 1) {  // Hillis-Steele inclusive scan
    int v = 0;
    if (t < BKT && t >= off) v = lscan[t - off];
    __syncthreads();
    if (t < BKT) lscan[t] += v;
    __syncthreads();
  }
  if (t < BKT) {
    int excl = rb + lscan[t] - lcnt[t];
    lcur[t] = excl;
    if (t < nn) {
      row_ptr[node0 + t] = excl;
      dinv[node0 + t] = rsqrtf((float)(lcnt[t] + 1));  // +1 self loop
    }
  }
  if (t == 0 && node0 + nn == n) row_ptr[n] = E;
  __syncthreads();
  for (int i = rb + t; i < re; i += 256) {
    unsigned int p = stage[i];
    int l = p >> 25;
    int pos = atomicAdd(&lcur[l], 1);       // LDS atomic cursor
    csr_src[pos] = (int)(p & SRCM);         // write within ~10KB L2-local window
  }
}

// ---------------- weight prep: transpose + bf16 (Wt[n][k]) ----------------
__global__ void prep_w_kernel(const void* __restrict__ W1, const void* __restrict__ W2,
                              ushort_t* __restrict__ Wt1, ushort_t* __restrict__ Wt2,
                              const int* __restrict__ flags) {
  int i = blockIdx.x * blockDim.x + threadIdx.x;
  bool f32 = flags[0] != 0;
  if (i < GCN_IN * GCN_HID) {                 // W1[k][n]
    int k = i >> 7, n = i & 127;
    float v = f32 ? ((const float*)W1)[i] : bf2f(((const ushort_t*)W1)[i]);
    Wt1[n * GCN_IN + k] = f2bf(v);
  }
  int j = i - GCN_IN * GCN_HID;
  if (j >= 0 && j < GCN_HID * GCN_OUT) {      // W2[k][n]
    int k = j >> 6, n = j & 63;
    float v = f32 ? ((const float*)W2)[j] : bf2f(((const ushort_t*)W2)[j]);
    Wt2[n * GCN_HID + k] = f2bf(v);
  }
}

// ---------------- MFMA GEMM1: C[M,NC] = A[M,K] @ Bt[NC,K]^T, bf16 out ----------------
template<int K, int NC, int A_MODE>
__global__ __launch_bounds__(256)
void gemm_mfma_kernel(const void* __restrict__ A, const ushort_t* __restrict__ Bt,
                      ushort_t* __restrict__ C, int M, const int* __restrict__ flags) {
  constexpr int KT = 32;
  constexpr int NT = NC / 32;
  __shared__ ushort_t As[32 * KT];
  __shared__ ushort_t Bs[NC * KT];
  const int tid = threadIdx.x;
  const int wv = tid >> 6;
  const int lane = tid & 63;
  const int ml = lane & 15;
  const int quad = lane >> 4;
  const int row0 = blockIdx.x * 32;
  const int mrow = (wv & 1) * 16 + ml;
  const int ncol0 = (wv >> 1) * (NC / 2);
  const bool aF32 = (A_MODE == 0) && (flags[0] != 0);
  f32x4 acc[NT] = {};

  for (int kt = 0; kt < K; kt += KT) {
    for (int c = tid; c < 32 * KT / 8; c += 256) {
      int r = c >> 2, cq = c & 3;
      ushort8 o;
      if (row0 + r < M) {
        if (aF32) {
          const float* ap = (const float*)A + (size_t)(row0 + r) * K + kt + cq * 8;
          float4 f0 = *(const float4*)ap;
          float4 f1 = *(const float4*)(ap + 4);
          o[0] = f2bf(f0.x); o[1] = f2bf(f0.y); o[2] = f2bf(f0.z); o[3] = f2bf(f0.w);
          o[4] = f2bf(f1.x); o[5] = f2bf(f1.y); o[6] = f2bf(f1.z); o[7] = f2bf(f1.w);
        } else {
          o = *(const ushort8*)((const ushort_t*)A + (size_t)(row0 + r) * K + kt + cq * 8);
        }
      } else {
        o = (ushort8)0;
      }
      *(ushort8*)&As[c * 8] = o;
    }
    for (int c = tid; c < NC * KT / 8; c += 256) {
      int n = c >> 2, cq = c & 3;
      *(ushort8*)&Bs[c * 8] = *(const ushort8*)(Bt + (size_t)n * K + kt + cq * 8);
    }
    __syncthreads();
    short8 af = *(const short8*)&As[mrow * KT + quad * 8];
#pragma unroll
    for (int t = 0; t < NT; ++t) {
      short8 bf = *(const short8*)&Bs[(ncol0 + t * 16 + ml) * KT + quad * 8];
      acc[t] = __builtin_amdgcn_mfma_f32_16x16x32_bf16(af, bf, acc[t], 0, 0, 0);
    }
    __syncthreads();
  }

  const int orow = row0 + (wv & 1) * 16 + quad * 4;
#pragma unroll
  for (int t = 0; t < NT; ++t) {
    int col = ncol0 + t * 16 + ml;
#pragma unroll
    for (int r = 0; r < 4; ++r) {
      if (orow + r < M)
        C[(size_t)(orow + r) * NC + col] = f2bf(acc[t][r]);
    }
  }
}

// ---------------- agg1 + GEMM2 fused: wave per node ----------------
// Gather loop (R12's lane-group form) -> shfl_xor butterfly leaves FULL sums in
// ALL lanes -> per-lane bias+relu gives hag[q*8+j] (f32, never stored) ->
// h2[lane] = sum_k hag[k]*W2t[lane][k] via __shfl const-lane broadcast + FMA.

__global__ void agg1_fused_kernel(const ushort_t* __restrict__ h,
                                  const int* __restrict__ row_ptr,
                                  const int* __restrict__ csr_src,
                                  const float* __restrict__ dinv,
                                  const void* __restrict__ bias,   // b1
                                  const ushort_t* __restrict__ wt2, // [64][128]
                                  ushort_t* __restrict__ h2out,     // [N,64]
                                  int n, const int* __restrict__ flags) {
  int wave = threadIdx.x >> 6;
  int lane = threadIdx.x & 63;
  int v = blockIdx.x * (blockDim.x >> 6) + wave;
  if (v >= n) return;
  const int q = lane & 15, g = lane >> 4;
  float acc[8] = {};
  int beg = row_ptr[v], end = row_ptr[v + 1];
  for (int base = beg; base < end; base += 64) {
    int navail = end - base; if (navail > 64) navail = 64;
    int sv = 0; float dv = 0.f;
    if (base + lane < end) { sv = csr_src[base + lane]; dv = dinv[sv]; }
    for (int j = 0; j < navail; j += 4) {
      int e = j + g;                       // <= 63 (j <= 60)
      int s = __shfl(sv, e);
      float ds = __shfl(dv, e);            // dinv[src]; 0 for tail lanes
      ushort8 hv = *(const ushort8*)(h + (size_t)s * GCN_HID + q * 8);
#pragma unroll
      for (int k = 0; k < 8; ++k) acc[k] = fmaf(ds, bf2f(hv[k]), acc[k]);
    }
  }
#pragma unroll
  for (int k = 0; k < 8; ++k) {            // butterfly: ALL lanes get full sums
    acc[k] += __shfl_xor(acc[k], 16);
    acc[k] += __shfl_xor(acc[k], 32);
  }
  // hag row slice for this lane's q (same in all 4 groups)
  float di = dinv[v];
  float sl = di * di;
  ushort8 hv = *(const ushort8*)(h + (size_t)v * GCN_HID + q * 8);
  const bool bF32 = flags[0] != 0;
  float hagv[8];
#pragma unroll
  for (int k = 0; k < 8; ++k) {
    float bv = bF32 ? ((const float*)bias)[q * 8 + k]
                    : bf2f(((const ushort_t*)bias)[q * 8 + k]);
    hagv[k] = fmaxf(di * acc[k] + sl * bf2f(hv[k]) + bv, 0.f);
  }
  // fused GEMM2 matvec: h2[lane] = sum_{kq,j} hag[kq*8+j] * W2t[lane][kq*8+j]
  float h2a = 0.f;
  const ushort_t* wrow = wt2 + (size_t)lane * GCN_HID;
#pragma unroll
  for (int kq = 0; kq < 16; ++kq) {
    ushort8 w = *(const ushort8*)(wrow + kq * 8);
#pragma unroll
    for (int j = 0; j < 8; ++j)
      h2a = fmaf(__shfl(hagv[j], kq), bf2f(w[j]), h2a);  // const-lane readlane
  }
  h2out[(size_t)v * GCN_OUT + lane] = f2bf(h2a);
}

// agg2: 8 groups x 8 lanes (row = 64 cols = 128B), 8 edges per VMEM inst.
__global__ void aggregate_out_kernel(const ushort_t* __restrict__ h,
                                     const int* __restrict__ row_ptr,
                                     const int* __restrict__ csr_src,
                                     const float* __restrict__ dinv,
                                     const void* __restrict__ bias,
                                     void* __restrict__ outp, int n,
                                     const int* __restrict__ flags) {
  int wave = threadIdx.x >> 6;
  int lane = threadIdx.x & 63;
  int v = blockIdx.x * (blockDim.x >> 6) + wave;
  if (v >= n) return;
  const int q = lane & 7, g = lane >> 3;
  float acc[8] = {};
  int beg = row_ptr[v], end = row_ptr[v + 1];
  for (int base = beg; base < end; base += 64) {
    int navail = end - base; if (navail > 64) navail = 64;
    int sv = 0; float dv = 0.f;
    if (base + lane < end) { sv = csr_src[base + lane]; dv = dinv[sv]; }
    for (int j = 0; j < navail; j += 8) {
      int e = j + g;                       // <= 63 (j <= 56)
      int s = __shfl(sv, e);
      float ds = __shfl(dv, e);            // dinv[src]
      ushort8 hv = *(const ushort8*)(h + (size_t)s * GCN_OUT + q * 8);
#pragma unroll
      for (int k = 0; k < 8; ++k) acc[k] = fmaf(ds, bf2f(hv[k]), acc[k]);
    }
  }
#pragma unroll
  for (int k = 0; k < 8; ++k) {
    acc[k] += __shfl_xor(acc[k], 8);
    acc[k] += __shfl_xor(acc[k], 16);
    acc[k] += __shfl_xor(acc[k], 32);
  }
  if (g == 0) {
    float di = dinv[v];
    float sl = di * di;
    ushort8 hv = *(const ushort8*)(h + (size_t)v * GCN_OUT + q * 8);
    const bool oF32 = flags[0] != 0;
    float r[8];
#pragma unroll
    for (int k = 0; k < 8; ++k) {
      float bv = oF32 ? ((const float*)bias)[q * 8 + k]
                      : bf2f(((const ushort_t*)bias)[q * 8 + k]);
      r[k] = di * acc[k] + sl * bf2f(hv[k]) + bv;
    }
    if (oF32) {
      float* op = (float*)outp + (size_t)v * GCN_OUT + q * 8;
      *(float4*)op = make_float4(r[0], r[1], r[2], r[3]);
      *(float4*)(op + 4) = make_float4(r[4], r[5], r[6], r[7]);
    } else {
      ushort8 o;
#pragma unroll
      for (int k = 0; k < 8; ++k) o[k] = f2bf(r[k]);
      *(ushort8*)((ushort_t*)outp + (size_t)v * GCN_OUT + q * 8) = o;
    }
  }
}

// ---------------- launch ----------------

extern "C" void kernel_launch(void* const* d_in, const int* in_sizes, int n_in,
                              void* d_out, int out_size, void* d_ws, size_t ws_size,
                              hipStream_t stream) {
  const void* x  = d_in[0];               // [N, 256] f32 (probed)
  const int*  ei = (const int*)d_in[1];   // [2, E] int32/int64 (probed)
  const void* W1 = d_in[2];               // [256,128]
  const void* b1 = d_in[3];               // [128]
  const void* W2 = d_in[4];               // [128,64]
  const void* b2 = d_in[5];               // [64]

  const int N = in_sizes[0] / GCN_IN;     // 30000
  const int E = in_sizes[1] / 2;          // 600000
  const int nsb  = (E + SBE - 1) / SBE;   // 147 superblocks (<=256 for scanC)
  const int nbin = (N + BKT - 1) / BKT;   // 235 buckets (<=256)

  size_t off = 0;
  auto alloc = [&](size_t bytes) -> void* {
    void* p = (char*)d_ws + off;
    off += (bytes + 255) & ~(size_t)255;
    return p;
  };
  int*          flags   = (int*)alloc(256);
  int*          binsum  = (int*)alloc(256 * 4);
  int*          Hmat    = (int*)alloc((size_t)nbin * nsb * 4);
  unsigned int* stage   = (unsigned int*)alloc((size_t)E * 4);
  int*          csr_src = (int*)alloc((size_t)E * 4);
  int*          row_ptr = (int*)alloc((size_t)(N + 1) * 4);
  float*        dinv    = (float*)alloc((size_t)N * 4);
  ushort_t*     h1      = (ushort_t*)alloc((size_t)N * GCN_HID * 2);  // bf16
  ushort_t*     h2      = (ushort_t*)alloc((size_t)N * GCN_OUT * 2);  // bf16
  ushort_t*     wt1     = (ushort_t*)alloc((size_t)GCN_HID * GCN_IN * 2);
  ushort_t*     wt2     = (ushort_t*)alloc((size_t)GCN_OUT * GCN_HID * 2);

  probe_kernel<<<1, 64, 0, stream>>>((const ushort_t*)x, ei, flags);
  hist_kernel<<<nsb, 256, 0, stream>>>(ei, E, Hmat, nsb, nbin, flags);
  scanA_kernel<<<nbin, 256, 0, stream>>>(Hmat, nsb, binsum);
  scanC_kernel<<<nbin, 256, 0, stream>>>(Hmat, nsb, binsum, nbin);
  stage2_kernel<<<nsb, 256, 0, stream>>>(ei, E, Hmat, nsb, nbin, stage, flags);
  scatter_kernel<<<nbin, 256, 0, stream>>>(stage, Hmat, nsb, nbin, csr_src,
                                           row_ptr, dinv, N, E);

  prep_w_kernel<<<(GCN_IN * GCN_HID + GCN_HID * GCN_OUT + 255) / 256, 256, 0, stream>>>(
      W1, W2, wt1, wt2, flags);

  // GEMM1: [N,256] @ [256,128] -> h1 bf16 (MFMA)
  gemm_mfma_kernel<GCN_IN, GCN_HID, 0>
      <<<(N + 31) / 32, 256, 0, stream>>>(x, wt1, h1, N, flags);

  int gAgg = (N + 3) / 4;  // 4 waves (nodes) per 256-thread block
  // agg1 + GEMM2 fused: h1 -> (A_norm, relu, @W2) -> h2
  agg1_fused_kernel<<<gAgg, 256, 0, stream>>>(h1, row_ptr, csr_src, dinv, b1,
                                              wt2, h2, N, flags);

  aggregate_out_kernel<<<gAgg, 256, 0, stream>>>(h2, row_ptr, csr_src,
                                                 dinv, b2, d_out, N, flags);
}

// Round 14
// 175.123 us; speedup vs baseline: 1.3538x; 1.3538x over previous
//
#include <hip/hip_runtime.h>

// GCNEncoder: h1 = x@W1; hag = relu(A_norm h1 + b1); h2 = hag@W2; out = A_norm h2 + b2
// A_norm (self loops): out[v] = dinv[v]^2 h[v] + sum_{e:dst=v} dinv[src]dinv[v] h[src]
// Established: float inputs f32 (probed), edges int64 (probed), output f32.
// h1/hag/h2 bf16. GEMMs = MFMA 16x16x32. Counting-sort CSR + hierarchical scan.
// R14: REVERTED R13's agg1+GEMM2 fusion (99us: 128 loop-indexed __shfl per wave
// = 128 serialized ds_bpermute on the DS pipe — shfl is only cheap at butterfly
// depth). Back to R12's split agg1 -> hag -> MFMA gemm2 (176.3us proven).
// Kept R13's scanB-merged-into-scanC (one fewer launch). 11 dispatches.

#define GCN_IN 256
#define GCN_HID 128
#define GCN_OUT 64

#define BKT 128          // nodes per bucket (dst >> 7)
#define SBE 4096         // edges per superblock
#define SRCM 0x1FFFFFFu  // 25-bit src mask

typedef unsigned short ushort_t;
typedef __attribute__((ext_vector_type(8))) short short8;     // 8 bf16 (4 VGPR)
typedef __attribute__((ext_vector_type(8))) unsigned short ushort8;
typedef __attribute__((ext_vector_type(4))) float f32x4;

__device__ inline float bf2f(ushort_t u) {
  union { unsigned int i; float f; } x; x.i = ((unsigned int)u) << 16; return x.f;
}
__device__ inline ushort_t f2bf(float f) {
  union { float f; unsigned int i; } u; u.f = f;
  unsigned int r = u.i + 0x7FFFu + ((u.i >> 16) & 1u);  // RNE
  return (ushort_t)(r >> 16);
}

// ---------------- dtype probe ----------------
// flags[0]: 1 = float inputs f32, 0 = bf16.  flags[1]: 1 = edges int64, 0 = int32.
__global__ void probe_kernel(const ushort_t* __restrict__ xu,
                             const int* __restrict__ ei,
                             int* __restrict__ flags) {
  int lane = threadIdx.x;  // 64 threads
  int c = 0, nz = 0;
  for (int i = lane; i < 128; i += 64) {
    ushort_t u = xu[2 * i];
    int e = (u >> 7) & 0xFF;
    c += (e >= 100 && e <= 140) ? 1 : 0;
    nz += (ei[2 * i + 1] != 0) ? 1 : 0;
  }
  for (int off = 32; off > 0; off >>= 1) {
    c += __shfl_down(c, off);
    nz += __shfl_down(nz, off);
  }
  if (lane == 0) {
    flags[0] = (c >= 64) ? 0 : 1;
    flags[1] = (nz == 0) ? 1 : 0;
  }
}

// ---- Pass A: per-superblock LDS bucket histogram -> Hmat[bin*nsb+sb] ----
__global__ void hist_kernel(const int* __restrict__ ei, int E,
                            int* __restrict__ Hmat, int nsb, int nbin,
                            const int* __restrict__ flags) {
  __shared__ int hist[256];
  int t = threadIdx.x;
  int sb = blockIdx.x;
  hist[t] = 0;
  __syncthreads();
  int base = sb * SBE;
  int end = base + SBE; if (end > E) end = E;
  bool i64 = flags[1] != 0;
  for (int i = base + t; i < end; i += 256) {
    int d = i64 ? ei[2 * E + 2 * i] : ei[E + i];
    atomicAdd(&hist[d >> 7], 1);            // LDS atomic
  }
  __syncthreads();
  for (int b = t; b < nbin; b += 256)
    Hmat[b * nsb + sb] = hist[b];
}

// ---- hierarchical exclusive scan of Hmat (bin-major) ----
// scanA: block b reduces its row Hmat[b*nsb .. +nsb) -> binsum[b] (raw sums)
__global__ void scanA_kernel(const int* __restrict__ Hmat, int nsb,
                             int* __restrict__ binsum) {
  __shared__ int red[256];
  int t = threadIdx.x;
  const int* row = Hmat + (size_t)blockIdx.x * nsb;
  int s = 0;
  for (int i = t; i < nsb; i += 256) s += row[i];
  red[t] = s;
  __syncthreads();
  for (int off = 128; off > 0; off >>= 1) {
    if (t < off) red[t] += red[t + off];
    __syncthreads();
  }
  if (t == 0) binsum[blockIdx.x] = red[0];
}

// scanC: block b (redundantly) scans raw binsum in LDS for its seed, then scans
// its own row in place. (scanB merged in.)
__global__ void scanC_kernel(int* __restrict__ Hmat, int nsb,
                             const int* __restrict__ binsum, int nbin) {
  __shared__ int bred[256];
  __shared__ int red[256];
  int t = threadIdx.x;
  int bs = (t < nbin) ? binsum[t] : 0;
  bred[t] = bs;
  __syncthreads();
  for (int off = 1; off < 256; off <<= 1) {
    int u = (t >= off) ? bred[t - off] : 0;
    __syncthreads();
    bred[t] += u;
    __syncthreads();
  }
  __shared__ int seed_sh;
  if (t == (int)blockIdx.x) seed_sh = bred[t] - bs;   // exclusive prefix of bins
  __syncthreads();
  int seed = seed_sh;
  int* row = Hmat + (size_t)blockIdx.x * nsb;
  int self = (t < nsb) ? row[t] : 0;
  red[t] = self;
  __syncthreads();
  for (int off = 1; off < 256; off <<= 1) {
    int u = (t >= off) ? red[t - off] : 0;
    __syncthreads();
    red[t] += u;
    __syncthreads();
  }
  if (t < nsb) row[t] = seed + red[t] - self;  // exclusive + seed
}

// ---- Pass C: stage edges bucket-sorted; LDS cursors seeded from scanned Hmat.
// Packed u32: src (25b) | dst_local (7b) << 25.
__global__ void stage2_kernel(const int* __restrict__ ei, int E,
                              const int* __restrict__ Hscan, int nsb, int nbin,
                              unsigned int* __restrict__ stage,
                              const int* __restrict__ flags) {
  __shared__ int cur[256];
  int t = threadIdx.x;
  int sb = blockIdx.x;
  for (int b = t; b < nbin; b += 256)
    cur[b] = Hscan[b * nsb + sb];
  __syncthreads();
  int base = sb * SBE;
  int end = base + SBE; if (end > E) end = E;
  bool i64 = flags[1] != 0;
  for (int i = base + t; i < end; i += 256) {
    int s, d;
    if (i64) { s = ei[2 * i]; d = ei[2 * E + 2 * i]; }
    else     { s = ei[i];     d = ei[E + i]; }
    int pos = atomicAdd(&cur[d >> 7], 1);   // LDS atomic
    stage[pos] = (unsigned int)s | ((unsigned int)(d & 127) << 25);
  }
}

// ---- Pass D: block per bucket. Local hist -> local scan -> row_ptr + dinv +
// LDS cursors -> scatter csr_src within the bucket's contiguous window.
__global__ void scatter_kernel(const unsigned int* __restrict__ stage,
                               const int* __restrict__ Hmat, int nsb, int nbin,
                               int* __restrict__ csr_src,
                               int* __restrict__ row_ptr,
                               float* __restrict__ dinv, int n, int E) {
  __shared__ int lcnt[BKT];
  __shared__ int lscan[BKT];
  __shared__ int lcur[BKT];
  const int t = threadIdx.x;                // 256 threads
  const int b = blockIdx.x;
  const int node0 = b * BKT;
  const int nn = (n - node0 < BKT) ? (n - node0) : BKT;
  const int rb = Hmat[b * nsb];
  const int re = (b + 1 < nbin) ? Hmat[(b + 1) * nsb] : E;
  if (t < BKT) lcnt[t] = 0;
  __syncthreads();
  for (int i = rb + t; i < re; i += 256)
    atomicAdd(&lcnt[stage[i] >> 25], 1);    // LDS atomic, 128 counters
  __syncthreads();
  if (t < BKT) lscan[t] = lcnt[t];
  __syncthreads();
  for (int off = 1; off < BKT; off <<= 1) {  // Hillis-Steele inclusive scan
    int v = 0;
    if (t < BKT && t >= off) v = lscan[t - off];
    __syncthreads();
    if (t < BKT) lscan[t] += v;
    __syncthreads();
  }
  if (t < BKT) {
    int excl = rb + lscan[t] - lcnt[t];
    lcur[t] = excl;
    if (t < nn) {
      row_ptr[node0 + t] = excl;
      dinv[node0 + t] = rsqrtf((float)(lcnt[t] + 1));  // +1 self loop
    }
  }
  if (t == 0 && node0 + nn == n) row_ptr[n] = E;
  __syncthreads();
  for (int i = rb + t; i < re; i += 256) {
    unsigned int p = stage[i];
    int l = p >> 25;
    int pos = atomicAdd(&lcur[l], 1);       // LDS atomic cursor
    csr_src[pos] = (int)(p & SRCM);         // write within ~10KB L2-local window
  }
}

// ---------------- weight prep: transpose + bf16 (Wt[n][k]) ----------------
__global__ void prep_w_kernel(const void* __restrict__ W1, const void* __restrict__ W2,
                              ushort_t* __restrict__ Wt1, ushort_t* __restrict__ Wt2,
                              const int* __restrict__ flags) {
  int i = blockIdx.x * blockDim.x + threadIdx.x;
  bool f32 = flags[0] != 0;
  if (i < GCN_IN * GCN_HID) {                 // W1[k][n]
    int k = i >> 7, n = i & 127;
    float v = f32 ? ((const float*)W1)[i] : bf2f(((const ushort_t*)W1)[i]);
    Wt1[n * GCN_IN + k] = f2bf(v);
  }
  int j = i - GCN_IN * GCN_HID;
  if (j >= 0 && j < GCN_HID * GCN_OUT) {      // W2[k][n]
    int k = j >> 6, n = j & 63;
    float v = f32 ? ((const float*)W2)[j] : bf2f(((const ushort_t*)W2)[j]);
    Wt2[n * GCN_HID + k] = f2bf(v);
  }
}

// ---------------- MFMA GEMM: C[M,NC] = A[M,K] @ Bt[NC,K]^T, bf16 in/out ----------------
template<int K, int NC, int A_MODE>
__global__ __launch_bounds__(256)
void gemm_mfma_kernel(const void* __restrict__ A, const ushort_t* __restrict__ Bt,
                      ushort_t* __restrict__ C, int M, const int* __restrict__ flags) {
  constexpr int KT = 32;
  constexpr int NT = NC / 32;
  __shared__ ushort_t As[32 * KT];
  __shared__ ushort_t Bs[NC * KT];
  const int tid = threadIdx.x;
  const int wv = tid >> 6;
  const int lane = tid & 63;
  const int ml = lane & 15;
  const int quad = lane >> 4;
  const int row0 = blockIdx.x * 32;
  const int mrow = (wv & 1) * 16 + ml;
  const int ncol0 = (wv >> 1) * (NC / 2);
  const bool aF32 = (A_MODE == 0) && (flags[0] != 0);
  f32x4 acc[NT] = {};

  for (int kt = 0; kt < K; kt += KT) {
    for (int c = tid; c < 32 * KT / 8; c += 256) {
      int r = c >> 2, cq = c & 3;
      ushort8 o;
      if (row0 + r < M) {
        if (aF32) {
          const float* ap = (const float*)A + (size_t)(row0 + r) * K + kt + cq * 8;
          float4 f0 = *(const float4*)ap;
          float4 f1 = *(const float4*)(ap + 4);
          o[0] = f2bf(f0.x); o[1] = f2bf(f0.y); o[2] = f2bf(f0.z); o[3] = f2bf(f0.w);
          o[4] = f2bf(f1.x); o[5] = f2bf(f1.y); o[6] = f2bf(f1.z); o[7] = f2bf(f1.w);
        } else {
          o = *(const ushort8*)((const ushort_t*)A + (size_t)(row0 + r) * K + kt + cq * 8);
        }
      } else {
        o = (ushort8)0;
      }
      *(ushort8*)&As[c * 8] = o;
    }
    for (int c = tid; c < NC * KT / 8; c += 256) {
      int n = c >> 2, cq = c & 3;
      *(ushort8*)&Bs[c * 8] = *(const ushort8*)(Bt + (size_t)n * K + kt + cq * 8);
    }
    __syncthreads();
    short8 af = *(const short8*)&As[mrow * KT + quad * 8];
#pragma unroll
    for (int t = 0; t < NT; ++t) {
      short8 bf = *(const short8*)&Bs[(ncol0 + t * 16 + ml) * KT + quad * 8];
      acc[t] = __builtin_amdgcn_mfma_f32_16x16x32_bf16(af, bf, acc[t], 0, 0, 0);
    }
    __syncthreads();
  }

  const int orow = row0 + (wv & 1) * 16 + quad * 4;
#pragma unroll
  for (int t = 0; t < NT; ++t) {
    int col = ncol0 + t * 16 + ml;
#pragma unroll
    for (int r = 0; r < 4; ++r) {
      if (orow + r < M)
        C[(size_t)(orow + r) * NC + col] = f2bf(acc[t][r]);
    }
  }
}

// ---------------- aggregation: wave per node, lane-group gathers ----------------
// agg1: 4 groups x 16 lanes; group g handles edge j+g, lane q loads ushort8 at
// col q*8 (16B/lane x 16 = full 256B row, coalesced). acc[8]/lane accumulates
// dinv[src]*h[src]; dinv[dst] applied once in epilogue.

__global__ void aggregate_relu_kernel(const ushort_t* __restrict__ h,
                                      const int* __restrict__ row_ptr,
                                      const int* __restrict__ csr_src,
                                      const float* __restrict__ dinv,
                                      const void* __restrict__ bias,
                                      ushort_t* __restrict__ outp, int n,
                                      const int* __restrict__ flags) {
  int wave = threadIdx.x >> 6;
  int lane = threadIdx.x & 63;
  int v = blockIdx.x * (blockDim.x >> 6) + wave;
  if (v >= n) return;
  const int q = lane & 15, g = lane >> 4;
  float acc[8] = {};
  int beg = row_ptr[v], end = row_ptr[v + 1];
  for (int base = beg; base < end; base += 64) {
    int navail = end - base; if (navail > 64) navail = 64;
    int sv = 0; float dv = 0.f;
    if (base + lane < end) { sv = csr_src[base + lane]; dv = dinv[sv]; }
    for (int j = 0; j < navail; j += 4) {
      int e = j + g;                       // <= 63 (j <= 60)
      int s = __shfl(sv, e);
      float ds = __shfl(dv, e);            // dinv[src]; 0 for tail lanes
      ushort8 hv = *(const ushort8*)(h + (size_t)s * GCN_HID + q * 8);
#pragma unroll
      for (int k = 0; k < 8; ++k) acc[k] = fmaf(ds, bf2f(hv[k]), acc[k]);
    }
  }
#pragma unroll
  for (int k = 0; k < 8; ++k) {
    acc[k] += __shfl_xor(acc[k], 16);
    acc[k] += __shfl_xor(acc[k], 32);
  }
  if (g == 0) {
    float di = dinv[v];
    float sl = di * di;
    ushort8 hv = *(const ushort8*)(h + (size_t)v * GCN_HID + q * 8);
    const bool bF32 = flags[0] != 0;
    ushort8 o;
#pragma unroll
    for (int k = 0; k < 8; ++k) {
      float bv = bF32 ? ((const float*)bias)[q * 8 + k]
                      : bf2f(((const ushort_t*)bias)[q * 8 + k]);
      o[k] = f2bf(fmaxf(di * acc[k] + sl * bf2f(hv[k]) + bv, 0.f));
    }
    *(ushort8*)(outp + (size_t)v * GCN_HID + q * 8) = o;
  }
}

// agg2: 8 groups x 8 lanes (row = 64 cols = 128B), 8 edges per VMEM inst.
__global__ void aggregate_out_kernel(const ushort_t* __restrict__ h,
                                     const int* __restrict__ row_ptr,
                                     const int* __restrict__ csr_src,
                                     const float* __restrict__ dinv,
                                     const void* __restrict__ bias,
                                     void* __restrict__ outp, int n,
                                     const int* __restrict__ flags) {
  int wave = threadIdx.x >> 6;
  int lane = threadIdx.x & 63;
  int v = blockIdx.x * (blockDim.x >> 6) + wave;
  if (v >= n) return;
  const int q = lane & 7, g = lane >> 3;
  float acc[8] = {};
  int beg = row_ptr[v], end = row_ptr[v + 1];
  for (int base = beg; base < end; base += 64) {
    int navail = end - base; if (navail > 64) navail = 64;
    int sv = 0; float dv = 0.f;
    if (base + lane < end) { sv = csr_src[base + lane]; dv = dinv[sv]; }
    for (int j = 0; j < navail; j += 8) {
      int e = j + g;                       // <= 63 (j <= 56)
      int s = __shfl(sv, e);
      float ds = __shfl(dv, e);            // dinv[src]
      ushort8 hv = *(const ushort8*)(h + (size_t)s * GCN_OUT + q * 8);
#pragma unroll
      for (int k = 0; k < 8; ++k) acc[k] = fmaf(ds, bf2f(hv[k]), acc[k]);
    }
  }
#pragma unroll
  for (int k = 0; k < 8; ++k) {
    acc[k] += __shfl_xor(acc[k], 8);
    acc[k] += __shfl_xor(acc[k], 16);
    acc[k] += __shfl_xor(acc[k], 32);
  }
  if (g == 0) {
    float di = dinv[v];
    float sl = di * di;
    ushort8 hv = *(const ushort8*)(h + (size_t)v * GCN_OUT + q * 8);
    const bool oF32 = flags[0] != 0;
    float r[8];
#pragma unroll
    for (int k = 0; k < 8; ++k) {
      float bv = oF32 ? ((const float*)bias)[q * 8 + k]
                      : bf2f(((const ushort_t*)bias)[q * 8 + k]);
      r[k] = di * acc[k] + sl * bf2f(hv[k]) + bv;
    }
    if (oF32) {
      float* op = (float*)outp + (size_t)v * GCN_OUT + q * 8;
      *(float4*)op = make_float4(r[0], r[1], r[2], r[3]);
      *(float4*)(op + 4) = make_float4(r[4], r[5], r[6], r[7]);
    } else {
      ushort8 o;
#pragma unroll
      for (int k = 0; k < 8; ++k) o[k] = f2bf(r[k]);
      *(ushort8*)((ushort_t*)outp + (size_t)v * GCN_OUT + q * 8) = o;
    }
  }
}

// ---------------- launch ----------------

extern "C" void kernel_launch(void* const* d_in, const int* in_sizes, int n_in,
                              void* d_out, int out_size, void* d_ws, size_t ws_size,
                              hipStream_t stream) {
  const void* x  = d_in[0];               // [N, 256] f32 (probed)
  const int*  ei = (const int*)d_in[1];   // [2, E] int32/int64 (probed)
  const void* W1 = d_in[2];               // [256,128]
  const void* b1 = d_in[3];               // [128]
  const void* W2 = d_in[4];               // [128,64]
  const void* b2 = d_in[5];               // [64]

  const int N = in_sizes[0] / GCN_IN;     // 30000
  const int E = in_sizes[1] / 2;          // 600000
  const int nsb  = (E + SBE - 1) / SBE;   // 147 superblocks (<=256 for scanC)
  const int nbin = (N + BKT - 1) / BKT;   // 235 buckets (<=256)

  size_t off = 0;
  auto alloc = [&](size_t bytes) -> void* {
    void* p = (char*)d_ws + off;
    off += (bytes + 255) & ~(size_t)255;
    return p;
  };
  int*          flags   = (int*)alloc(256);
  int*          binsum  = (int*)alloc(256 * 4);
  int*          Hmat    = (int*)alloc((size_t)nbin * nsb * 4);
  unsigned int* stage   = (unsigned int*)alloc((size_t)E * 4);
  int*          csr_src = (int*)alloc((size_t)E * 4);
  int*          row_ptr = (int*)alloc((size_t)(N + 1) * 4);
  float*        dinv    = (float*)alloc((size_t)N * 4);
  ushort_t*     h1      = (ushort_t*)alloc((size_t)N * GCN_HID * 2);  // bf16
  ushort_t*     hag     = (ushort_t*)alloc((size_t)N * GCN_HID * 2);  // bf16
  ushort_t*     wt1     = (ushort_t*)alloc((size_t)GCN_HID * GCN_IN * 2);
  ushort_t*     wt2     = (ushort_t*)alloc((size_t)GCN_OUT * GCN_HID * 2);
  ushort_t*     h2      = h1;  // h1 dead after hag; reuse for GEMM2 output

  probe_kernel<<<1, 64, 0, stream>>>((const ushort_t*)x, ei, flags);
  hist_kernel<<<nsb, 256, 0, stream>>>(ei, E, Hmat, nsb, nbin, flags);
  scanA_kernel<<<nbin, 256, 0, stream>>>(Hmat, nsb, binsum);
  scanC_kernel<<<nbin, 256, 0, stream>>>(Hmat, nsb, binsum, nbin);
  stage2_kernel<<<nsb, 256, 0, stream>>>(ei, E, Hmat, nsb, nbin, stage, flags);
  scatter_kernel<<<nbin, 256, 0, stream>>>(stage, Hmat, nsb, nbin, csr_src,
                                           row_ptr, dinv, N, E);

  prep_w_kernel<<<(GCN_IN * GCN_HID + GCN_HID * GCN_OUT + 255) / 256, 256, 0, stream>>>(
      W1, W2, wt1, wt2, flags);

  // GEMM1: [N,256] @ [256,128] -> h1 bf16 (MFMA)
  gemm_mfma_kernel<GCN_IN, GCN_HID, 0>
      <<<(N + 31) / 32, 256, 0, stream>>>(x, wt1, h1, N, flags);

  int gAgg = (N + 3) / 4;  // 4 waves (nodes) per 256-thread block
  aggregate_relu_kernel<<<gAgg, 256, 0, stream>>>(h1, row_ptr, csr_src,
                                                  dinv, b1, hag, N, flags);

  // GEMM2: [N,128] @ [128,64] -> h2 bf16 (MFMA, A bf16)
  gemm_mfma_kernel<GCN_HID, GCN_OUT, 2>
      <<<(N + 31) / 32, 256, 0, stream>>>(hag, wt2, h2, N, flags);

  aggregate_out_kernel<<<gAgg, 256, 0, stream>>>(h2, row_ptr, csr_src,
                                                 dinv, b2, d_out, N, flags);
}